// Round 6
// baseline (280.075 us; speedup 1.0000x reference)
//
#include <hip/hip_runtime.h>

#define IN_DIM 128
#define LDT 136           // padded per-wave scratch row stride (ushorts)

typedef short v8s __attribute__((ext_vector_type(8)));   // 8 bf16 (4 VGPRs)
typedef float v4f __attribute__((ext_vector_type(4)));   // MFMA acc

__device__ inline unsigned short f2bf(float f) {
    unsigned int u = __float_as_uint(f);
    u += 0x7FFFu + ((u >> 16) & 1u);          // round-to-nearest-even
    return (unsigned short)(u >> 16);
}
__device__ inline float bf2f(unsigned short h) {
    return __uint_as_float((unsigned int)h << 16);
}

// ---------------------------------------------------------------------------
// setup: blocks [0,nbFlag) mark flag[node_idx]; remaining 128 blocks convert
// W1/W2 (fp32, k-major) -> transposed bf16 hi/lo Wt[n][k] (split-W kills the
// correlated weight-rounding error the 16-edge mean can't average down).
// ---------------------------------------------------------------------------
__global__ __launch_bounds__(256) void setup(
    const int* __restrict__ node_idx, int* __restrict__ flag, int B,
    const float* __restrict__ W1, const float* __restrict__ W2,
    unsigned short* __restrict__ Wt1h, unsigned short* __restrict__ Wt1l,
    unsigned short* __restrict__ Wt2h, unsigned short* __restrict__ Wt2l,
    int nbFlag)
{
    int bid = blockIdx.x;
    if (bid < nbFlag) {
        int i = bid * 256 + threadIdx.x;
        if (i < B) flag[node_idx[i]] = 1;
    } else {
        int i = (bid - nbFlag) * 256 + threadIdx.x;   // 0..32767
        int m = i >> 14, rem = i & 16383;
        int n = rem >> 7, k = rem & 127;
        float wv = (m ? W2 : W1)[k * 128 + n];
        unsigned short hi = f2bf(wv);
        unsigned short lo = f2bf(wv - bf2f(hi));
        (m ? Wt2h : Wt1h)[n * 128 + k] = hi;
        (m ? Wt2l : Wt1l)[n * 128 + k] = lo;
    }
}

// ---------------------------------------------------------------------------
// Barrier-free MFMA MLP: Hb = bf16(tanh(X@W1+b1)@W2+b2).
// Block = 64 rows x 128 cols, 4 waves, wave w owns the 16-row tile
// [R0+w*16, R0+w*16+16). Phase-2 A-rows == the wave's own phase-1 C-rows ->
// tanh intermediate is wave-private LDS scratch; NO __syncthreads anywhere.
// Grid 782 (~3 waves/SIMD) for latency hiding — this was the R5 limiter
// (391 blocks -> Occupancy 13%).
// A-frags: global fp32 X, inline bf16 cvt. B-frags: global Wt hi/lo
// (16 KB/chunk, L1-resident; all waves on a CU share the same stream).
// Epilogues: C-layout scatter -> per-wave LDS (bf16, +8 pad) -> uint4
// reads -> coalesced dwordx4 stores (H bf16). LDS 17408 B.
// Frag maps (m89/m91/m120-verified): A[m=lane&15][k=quad*8+j];
// B[n=lane&15][k=quad*8+j]; C/D col=lane&15, row=quad*4+reg.
// ---------------------------------------------------------------------------
__global__ __launch_bounds__(256, 4) void mlp_mfma(
    const float* __restrict__ X,
    const unsigned short* __restrict__ Wt1h, const unsigned short* __restrict__ Wt1l,
    const unsigned short* __restrict__ Wt2h, const unsigned short* __restrict__ Wt2l,
    const float* __restrict__ b1, const float* __restrict__ b2,
    unsigned short* __restrict__ Hb, int nrows)
{
    __shared__ unsigned short Ts[4 * 16 * LDT];   // 17408 B, per-wave slices
    const int t    = threadIdx.x;
    const int w    = t >> 6;
    const int lane = t & 63;
    const int l15  = lane & 15;
    const int quad = lane >> 4;
    const int R0   = blockIdx.x * 64;
    const int wrow = w * 16;
    unsigned short* Tw = &Ts[w * 16 * LDT];

    v4f acc[8];
#pragma unroll
    for (int ct = 0; ct < 8; ++ct)
        acc[ct] = (v4f){0.f, 0.f, 0.f, 0.f};

    // ---- phase 1: T = tanh(X @ W1 + b1) ----
    for (int kk = 0; kk < 4; ++kk) {
        int grow = R0 + wrow + l15;
        grow = grow < nrows ? grow : nrows - 1;
        const float* xp = &X[(size_t)grow * 128 + kk * 32 + quad * 8];
        float4 x0 = *(const float4*)xp;
        float4 x1 = *(const float4*)(xp + 4);
        v8s a;
        a[0] = (short)f2bf(x0.x); a[1] = (short)f2bf(x0.y);
        a[2] = (short)f2bf(x0.z); a[3] = (short)f2bf(x0.w);
        a[4] = (short)f2bf(x1.x); a[5] = (short)f2bf(x1.y);
        a[6] = (short)f2bf(x1.z); a[7] = (short)f2bf(x1.w);
#pragma unroll
        for (int ct = 0; ct < 8; ++ct) {
            size_t bo = (size_t)(ct * 16 + l15) * 128 + kk * 32 + quad * 8;
            v8s bh = *(const v8s*)&Wt1h[bo];
            v8s bl = *(const v8s*)&Wt1l[bo];
            acc[ct] = __builtin_amdgcn_mfma_f32_16x16x32_bf16(a, bh, acc[ct], 0, 0, 0);
            acc[ct] = __builtin_amdgcn_mfma_f32_16x16x32_bf16(a, bl, acc[ct], 0, 0, 0);
        }
    }
    // epilogue 1: tanh -> per-wave LDS (bf16, C-layout scatter)
#pragma unroll
    for (int ct = 0; ct < 8; ++ct) {
        float bias = b1[ct * 16 + l15];
#pragma unroll
        for (int r = 0; r < 4; ++r)
            Tw[(quad * 4 + r) * LDT + ct * 16 + l15] =
                f2bf(tanhf(acc[ct][r] + bias));
        acc[ct] = (v4f){0.f, 0.f, 0.f, 0.f};
    }
    asm volatile("s_waitcnt lgkmcnt(0)" ::: "memory");  // wave-local W->R order

    // ---- phase 2: H = T @ W2 + b2 ----
    for (int kk = 0; kk < 4; ++kk) {
        v8s a = *(const v8s*)&Tw[l15 * LDT + kk * 32 + quad * 8];
#pragma unroll
        for (int ct = 0; ct < 8; ++ct) {
            size_t bo = (size_t)(ct * 16 + l15) * 128 + kk * 32 + quad * 8;
            v8s bh = *(const v8s*)&Wt2h[bo];
            v8s bl = *(const v8s*)&Wt2l[bo];
            acc[ct] = __builtin_amdgcn_mfma_f32_16x16x32_bf16(a, bh, acc[ct], 0, 0, 0);
            acc[ct] = __builtin_amdgcn_mfma_f32_16x16x32_bf16(a, bl, acc[ct], 0, 0, 0);
        }
    }
    asm volatile("s_waitcnt lgkmcnt(0)" ::: "memory");  // phase-2 reads done
    // epilogue 2: acc -> per-wave LDS (bf16) -> coalesced dwordx4 H stores
#pragma unroll
    for (int ct = 0; ct < 8; ++ct) {
        float bias = b2[ct * 16 + l15];
#pragma unroll
        for (int r = 0; r < 4; ++r)
            Tw[(quad * 4 + r) * LDT + ct * 16 + l15] = f2bf(acc[ct][r] + bias);
    }
    asm volatile("s_waitcnt lgkmcnt(0)" ::: "memory");
#pragma unroll
    for (int i = 0; i < 4; ++i) {
        int lr = i * 4 + quad;             // 0..15
        int c  = l15;                      // 16 chunks x 8 ushorts = 128
        uint4 v = *(const uint4*)&Tw[lr * LDT + c * 8];
        int grow = R0 + wrow + lr;
        if (grow < nrows)
            *(uint4*)&Hb[(size_t)grow * 128 + c * 8] = v;
    }
}

// deg[src] = kept-edge count (== row_sum exactly: kept weights are 1.0).
__global__ __launch_bounds__(256) void edge_count(
    const int* __restrict__ edges, const int* __restrict__ flag,
    const int* __restrict__ indp, int* __restrict__ deg, int E)
{
    const float selfw = (*indp < 2) ? 1.0f : 0.0f;
    int e = blockIdx.x * blockDim.x + threadIdx.x;
    if (e < E) {
        int2 ed = ((const int2*)edges)[e];
        if (flag[ed.x] != 0 && (ed.x != ed.y || selfw != 0.0f))
            atomicAdd(&deg[ed.x], 1);
    }
}

// ---------------------------------------------------------------------------
// Single-block exclusive scan of deg[N] -> rowstart[N] (+total at [N]).
// 1024 threads x ceil(N/1024) contiguous elems each; deg read twice (L2-hot).
// Replaces the R5 scan1+scan2+scan3 triple (2 fewer launches).
// ---------------------------------------------------------------------------
__global__ __launch_bounds__(1024) void scan_all(
    const int* __restrict__ deg, int* __restrict__ rowstart, int N)
{
    const int t  = threadIdx.x;
    const int ch = (N + 1023) >> 10;
    const int i0 = t * ch;
    int s = 0;
    for (int j = 0; j < ch; ++j) {
        int i = i0 + j;
        if (i < N) s += deg[i];
    }
    __shared__ int sc[1024];
    sc[t] = s;
    __syncthreads();
#pragma unroll
    for (int off = 1; off < 1024; off <<= 1) {
        int u = 0;
        if (t >= off) u = sc[t - off];
        __syncthreads();
        if (t >= off) sc[t] += u;
        __syncthreads();
    }
    int run = sc[t] - s;   // exclusive prefix of this thread's chunk
    for (int j = 0; j < ch; ++j) {
        int i = i0 + j;
        if (i < N) { rowstart[i] = run; run += deg[i]; }
    }
    if (t == 1023) rowstart[N] = sc[1023];
}

__global__ __launch_bounds__(256) void edge_fill_csr(
    const int* __restrict__ edges, const int* __restrict__ flag,
    const int* __restrict__ indp, const int* __restrict__ rowstart,
    int* __restrict__ cursor, unsigned short* __restrict__ col, int E)
{
    const float selfw = (*indp < 2) ? 1.0f : 0.0f;
    int e = blockIdx.x * blockDim.x + threadIdx.x;
    if (e < E) {
        int2 ed = ((const int2*)edges)[e];
        if (flag[ed.x] != 0 && (ed.x != ed.y || selfw != 0.0f)) {
            int p = atomicAdd(&cursor[ed.x], 1);
            col[rowstart[ed.x] + p] = (unsigned short)ed.y;
        }
    }
}

// ---------------------------------------------------------------------------
// Fused aggregate+gather: one wave per OUTPUT row b. v=node_idx[b];
// out[b] = (sum_{CSR(v)} Hb[dst]) / max(deg,1). Duplicate v's (~10%)
// recompute — cheaper than materializing acc[] (saves 5MB wr + 5MB rd +
// one launch). Hb bf16: 4B/lane -> 256B coalesced row gather, no atomics.
// ---------------------------------------------------------------------------
__global__ __launch_bounds__(256) void aggregate_out(
    const int* __restrict__ node_idx, const int* __restrict__ rowstart,
    const unsigned short* __restrict__ col, const unsigned short* __restrict__ Hb,
    float* __restrict__ out, int B)
{
    int b = (int)((blockIdx.x * blockDim.x + threadIdx.x) >> 6);
    if (b >= B) return;
    int lane = threadIdx.x & 63;
    int v = node_idx[b];
    int s = rowstart[v], e = rowstart[v + 1];
    float ax = 0.f, ay = 0.f, bx = 0.f, by = 0.f;
    int i = s;
    for (; i + 1 < e; i += 2) {
        int d0 = col[i], d1 = col[i + 1];
        unsigned int u0 = *(const unsigned int*)&Hb[(size_t)d0 * 128 + lane * 2];
        unsigned int u1 = *(const unsigned int*)&Hb[(size_t)d1 * 128 + lane * 2];
        ax += bf2f((unsigned short)(u0 & 0xFFFFu));
        ay += bf2f((unsigned short)(u0 >> 16));
        bx += bf2f((unsigned short)(u1 & 0xFFFFu));
        by += bf2f((unsigned short)(u1 >> 16));
    }
    if (i < e) {
        int d0 = col[i];
        unsigned int u0 = *(const unsigned int*)&Hb[(size_t)d0 * 128 + lane * 2];
        ax += bf2f((unsigned short)(u0 & 0xFFFFu));
        ay += bf2f((unsigned short)(u0 >> 16));
    }
    float den = (e > s) ? (float)(e - s) : 1.0f;
    *(float2*)&out[(size_t)b * 128 + lane * 2] =
        make_float2((ax + bx) / den, (ay + by) / den);
}

extern "C" void kernel_launch(void* const* d_in, const int* in_sizes, int n_in,
                              void* d_out, int out_size, void* d_ws, size_t ws_size,
                              hipStream_t stream)
{
    const int*   edges    = (const int*)d_in[0];
    const int*   node_idx = (const int*)d_in[1];
    const float* X        = (const float*)d_in[2];
    const float* W1       = (const float*)d_in[3];
    const float* b1       = (const float*)d_in[4];
    const float* W2       = (const float*)d_in[5];
    const float* b2       = (const float*)d_in[6];
    const int*   indp     = (const int*)d_in[7];

    const int E = in_sizes[0] / 2;
    const int B = in_sizes[1];
    const int N = in_sizes[2] / IN_DIM;
    const int nbFlag = (B + 255) / 256;                 // 40

    // workspace layout:
    // [flag N][deg N][cursor N][16B] | [rowstart N+1] [Hb N*128 bf16]
    // [col E u16] [Wt1h][Wt1l][Wt2h][Wt2l] (each 16384 bf16)
    char* ws = (char*)d_ws;
    size_t off = 0;
    int* flag   = (int*)(ws + off); off += (size_t)N * 4;
    int* deg    = (int*)(ws + off); off += (size_t)N * 4;
    int* cursor = (int*)(ws + off); off += (size_t)N * 4;
    off += 16;
    const size_t zbytes = off;
    int* rowstart = (int*)(ws + off); off += (size_t)(N + 1) * 4;
    off = (off + 15) & ~(size_t)15;
    unsigned short* Hb = (unsigned short*)(ws + off); off += (size_t)N * IN_DIM * 2;
    unsigned short* col = (unsigned short*)(ws + off); off += (size_t)E * 2;
    off = (off + 15) & ~(size_t)15;
    unsigned short* Wt1h = (unsigned short*)(ws + off); off += 16384 * 2;
    unsigned short* Wt1l = (unsigned short*)(ws + off); off += 16384 * 2;
    unsigned short* Wt2h = (unsigned short*)(ws + off); off += 16384 * 2;
    unsigned short* Wt2l = (unsigned short*)(ws + off); off += 16384 * 2;

    hipMemsetAsync(d_ws, 0, zbytes, stream);

    hipLaunchKernelGGL(setup, dim3(nbFlag + 128), dim3(256), 0, stream,
                       node_idx, flag, B, W1, W2, Wt1h, Wt1l, Wt2h, Wt2l,
                       nbFlag);
    hipLaunchKernelGGL(mlp_mfma, dim3((N + 63) / 64), dim3(256), 0, stream,
                       X, Wt1h, Wt1l, Wt2h, Wt2l, b1, b2, Hb, N);
    hipLaunchKernelGGL(edge_count, dim3((E + 255) / 256), dim3(256), 0, stream,
                       edges, flag, indp, deg, E);
    hipLaunchKernelGGL(scan_all, dim3(1), dim3(1024), 0, stream,
                       deg, rowstart, N);
    hipLaunchKernelGGL(edge_fill_csr, dim3((E + 255) / 256), dim3(256), 0,
                       stream, edges, flag, indp, rowstart, cursor, col, E);
    hipLaunchKernelGGL(aggregate_out, dim3((B * 64 + 255) / 256), dim3(256), 0,
                       stream, node_idx, rowstart, col, Hb, (float*)d_out, B);
}

// Round 7
// 214.303 us; speedup vs baseline: 1.3069x; 1.3069x over previous
//
#include <hip/hip_runtime.h>

#define IN_DIM 128
#define SCAN_CHUNK 1024   // elements per block in scan1 (256 threads x 4)
#define LDT 136           // padded per-wave scratch row stride (ushorts)

typedef short v8s __attribute__((ext_vector_type(8)));   // 8 bf16 (4 VGPRs)
typedef float v4f __attribute__((ext_vector_type(4)));   // MFMA acc

__device__ inline unsigned short f2bf(float f) {
    unsigned int u = __float_as_uint(f);
    u += 0x7FFFu + ((u >> 16) & 1u);          // round-to-nearest-even
    return (unsigned short)(u >> 16);
}
__device__ inline float bf2f(unsigned short h) {
    return __uint_as_float((unsigned int)h << 16);
}

// ---------------------------------------------------------------------------
// setup: W1/W2 (fp32, k-major) -> transposed bf16 Wt[n][k]. 32768 elems.
// Single-rounding W (no hi/lo split): measured-safe error budget (see R6->R7
// analysis: adds ~1e-3 sigma per layer; threshold 0.0231).
// ---------------------------------------------------------------------------
__global__ __launch_bounds__(256) void setup(
    const float* __restrict__ W1, const float* __restrict__ W2,
    unsigned short* __restrict__ Wt1, unsigned short* __restrict__ Wt2)
{
    int i = blockIdx.x * 256 + threadIdx.x;   // 0..32767
    int m = i >> 14, rem = i & 16383;
    int n = rem >> 7, k = rem & 127;
    float wv = (m ? W2 : W1)[k * 128 + n];
    (m ? Wt2 : Wt1)[n * 128 + k] = f2bf(wv);
}

// ---------------------------------------------------------------------------
// Barrier-free MFMA MLP: Hb = bf16(tanh(X@W1+b1)@W2+b2).
// R5-proven shape: block = 128 rows x 128 cols, 4 waves, wave w owns rows
// [w*32, w*32+32) as 2 row-tiles of 16. Phase-2 A-rows == the wave's own
// phase-1 C-rows -> tanh intermediate is wave-private LDS; NO __syncthreads.
// Single-W B-frags straight from global (16 KB/chunk L1-resident); 32
// B-loads + 8 X-loads per wave per phase, kk fully unrolled so the compiler
// can batch loads (launch_bounds (256,2): grid-limited occupancy, give VGPRs).
// Frag maps (m89/m91/m120-verified): A[m=lane&15][k=quad*8+j];
// B[n=lane&15][k=quad*8+j]; C/D col=lane&15, row=quad*4+reg.
// ---------------------------------------------------------------------------
__global__ __launch_bounds__(256, 2) void mlp_mfma(
    const float* __restrict__ X,
    const unsigned short* __restrict__ Wt1, const unsigned short* __restrict__ Wt2,
    const float* __restrict__ b1, const float* __restrict__ b2,
    unsigned short* __restrict__ Hb, int nrows)
{
    __shared__ unsigned short Ts[4 * 32 * LDT];   // 34816 B, per-wave slices
    const int t    = threadIdx.x;
    const int w    = t >> 6;
    const int lane = t & 63;
    const int l15  = lane & 15;
    const int quad = lane >> 4;
    const int R0   = blockIdx.x * 128;
    const int wrow = w * 32;
    unsigned short* Tw = &Ts[w * 32 * LDT];

    v4f acc[2][8];
#pragma unroll
    for (int rt = 0; rt < 2; ++rt)
#pragma unroll
        for (int ct = 0; ct < 8; ++ct)
            acc[rt][ct] = (v4f){0.f, 0.f, 0.f, 0.f};

    // ---- phase 1: T = tanh(X @ W1 + b1) ----
#pragma unroll
    for (int kk = 0; kk < 4; ++kk) {
        v8s a[2];
#pragma unroll
        for (int rt = 0; rt < 2; ++rt) {
            int grow = R0 + wrow + rt * 16 + l15;
            grow = grow < nrows ? grow : nrows - 1;
            const float* xp = &X[(size_t)grow * 128 + kk * 32 + quad * 8];
            float4 x0 = *(const float4*)xp;
            float4 x1 = *(const float4*)(xp + 4);
            v8s av;
            av[0] = (short)f2bf(x0.x); av[1] = (short)f2bf(x0.y);
            av[2] = (short)f2bf(x0.z); av[3] = (short)f2bf(x0.w);
            av[4] = (short)f2bf(x1.x); av[5] = (short)f2bf(x1.y);
            av[6] = (short)f2bf(x1.z); av[7] = (short)f2bf(x1.w);
            a[rt] = av;
        }
#pragma unroll
        for (int ct = 0; ct < 8; ++ct) {
            v8s b = *(const v8s*)&Wt1[(size_t)(ct * 16 + l15) * 128 + kk * 32 + quad * 8];
#pragma unroll
            for (int rt = 0; rt < 2; ++rt)
                acc[rt][ct] = __builtin_amdgcn_mfma_f32_16x16x32_bf16(
                    a[rt], b, acc[rt][ct], 0, 0, 0);
        }
    }
    // epilogue 1: tanh -> per-wave LDS (bf16, C-layout scatter)
#pragma unroll
    for (int ct = 0; ct < 8; ++ct) {
        float bias = b1[ct * 16 + l15];
#pragma unroll
        for (int rt = 0; rt < 2; ++rt) {
#pragma unroll
            for (int r = 0; r < 4; ++r)
                Tw[(rt * 16 + quad * 4 + r) * LDT + ct * 16 + l15] =
                    f2bf(tanhf(acc[rt][ct][r] + bias));
            acc[rt][ct] = (v4f){0.f, 0.f, 0.f, 0.f};
        }
    }
    asm volatile("s_waitcnt lgkmcnt(0)" ::: "memory");  // wave-local W->R order

    // ---- phase 2: H = T @ W2 + b2 ----
#pragma unroll
    for (int kk = 0; kk < 4; ++kk) {
        v8s a[2];
#pragma unroll
        for (int rt = 0; rt < 2; ++rt)
            a[rt] = *(const v8s*)&Tw[(rt * 16 + l15) * LDT + kk * 32 + quad * 8];
#pragma unroll
        for (int ct = 0; ct < 8; ++ct) {
            v8s b = *(const v8s*)&Wt2[(size_t)(ct * 16 + l15) * 128 + kk * 32 + quad * 8];
#pragma unroll
            for (int rt = 0; rt < 2; ++rt)
                acc[rt][ct] = __builtin_amdgcn_mfma_f32_16x16x32_bf16(
                    a[rt], b, acc[rt][ct], 0, 0, 0);
        }
    }
    asm volatile("s_waitcnt lgkmcnt(0)" ::: "memory");  // phase-2 reads done
    // epilogue 2: acc -> per-wave LDS (bf16) -> coalesced dwordx4 H stores
#pragma unroll
    for (int ct = 0; ct < 8; ++ct) {
        float bias = b2[ct * 16 + l15];
#pragma unroll
        for (int rt = 0; rt < 2; ++rt)
#pragma unroll
            for (int r = 0; r < 4; ++r)
                Tw[(rt * 16 + quad * 4 + r) * LDT + ct * 16 + l15] =
                    f2bf(acc[rt][ct][r] + bias);
    }
    asm volatile("s_waitcnt lgkmcnt(0)" ::: "memory");
#pragma unroll
    for (int i = 0; i < 8; ++i) {
        int lr = i * 4 + quad;             // 0..31
        int c  = l15;                      // 16 chunks x 8 ushorts = 128
        uint4 v = *(const uint4*)&Tw[lr * LDT + c * 8];
        int grow = R0 + wrow + lr;
        if (grow < nrows)
            *(uint4*)&Hb[(size_t)grow * 128 + c * 8] = v;
    }
}

// ---------------------------------------------------------------------------
// deg[src] over ALL nodes (no flag gather — CSR built for the full graph;
// == row_sum exactly: kept weights are all 1.0, zero-weight self edges are
// excluded from both numerator and denominator).
// ---------------------------------------------------------------------------
__global__ __launch_bounds__(256) void edge_count(
    const int* __restrict__ edges, const int* __restrict__ indp,
    int* __restrict__ deg, int E)
{
    const float selfw = (*indp < 2) ? 1.0f : 0.0f;
    int e = blockIdx.x * blockDim.x + threadIdx.x;
    if (e < E) {
        int2 ed = ((const int2*)edges)[e];
        if (ed.x != ed.y || selfw != 0.0f)
            atomicAdd(&deg[ed.x], 1);
    }
}

// ---- 3-step exclusive scan of deg[N] -> rowstart[N] (+ total) — R5-proven ----
__global__ __launch_bounds__(256) void scan1(
    const int* __restrict__ deg, int* __restrict__ rowstart,
    int* __restrict__ bsum, int N)
{
    int t = threadIdx.x;
    int base = blockIdx.x * SCAN_CHUNK;
    int v[4], s = 0;
#pragma unroll
    for (int j = 0; j < 4; ++j) {
        int i = base + t * 4 + j;
        v[j] = (i < N) ? deg[i] : 0;
        s += v[j];
    }
    __shared__ int sc[256];
    sc[t] = s;
    __syncthreads();
#pragma unroll
    for (int off = 1; off < 256; off <<= 1) {
        int u = 0;
        if (t >= off) u = sc[t - off];
        __syncthreads();
        if (t >= off) sc[t] += u;
        __syncthreads();
    }
    int run = sc[t] - s;
#pragma unroll
    for (int j = 0; j < 4; ++j) {
        int i = base + t * 4 + j;
        if (i < N) rowstart[i] = run;
        run += v[j];
    }
    if (t == 255) bsum[blockIdx.x] = sc[255];
}

__global__ void scan2(const int* __restrict__ bsum, int* __restrict__ bbase,
                      int* __restrict__ rowstart, int nb, int N)
{
    if (threadIdx.x == 0 && blockIdx.x == 0) {
        int run = 0;
        for (int i = 0; i < nb; ++i) { bbase[i] = run; run += bsum[i]; }
        rowstart[N] = run;
    }
}

__global__ __launch_bounds__(256) void scan3(
    int* __restrict__ rowstart, const int* __restrict__ bbase, int N)
{
    int i = blockIdx.x * blockDim.x + threadIdx.x;
    if (i < N) rowstart[i] += bbase[i >> 10];
}

__global__ __launch_bounds__(256) void edge_fill_csr(
    const int* __restrict__ edges, const int* __restrict__ indp,
    const int* __restrict__ rowstart, int* __restrict__ cursor,
    unsigned short* __restrict__ col, int E)
{
    const float selfw = (*indp < 2) ? 1.0f : 0.0f;
    int e = blockIdx.x * blockDim.x + threadIdx.x;
    if (e < E) {
        int2 ed = ((const int2*)edges)[e];
        if (ed.x != ed.y || selfw != 0.0f) {
            int p = atomicAdd(&cursor[ed.x], 1);
            col[rowstart[ed.x] + p] = (unsigned short)ed.y;
        }
    }
}

// ---------------------------------------------------------------------------
// Fused aggregate+gather (R6-measured-good): one wave per OUTPUT row b.
// v=node_idx[b]; out[b] = (sum_{CSR(v)} Hb[dst]) / max(deg,1).
// Hb bf16: 4B/lane -> 256B coalesced row gather, no atomics.
// ---------------------------------------------------------------------------
__global__ __launch_bounds__(256) void aggregate_out(
    const int* __restrict__ node_idx, const int* __restrict__ rowstart,
    const unsigned short* __restrict__ col, const unsigned short* __restrict__ Hb,
    float* __restrict__ out, int B)
{
    int b = (int)((blockIdx.x * blockDim.x + threadIdx.x) >> 6);
    if (b >= B) return;
    int lane = threadIdx.x & 63;
    int v = node_idx[b];
    int s = rowstart[v], e = rowstart[v + 1];
    float ax = 0.f, ay = 0.f, bx = 0.f, by = 0.f;
    int i = s;
    for (; i + 1 < e; i += 2) {
        int d0 = col[i], d1 = col[i + 1];
        unsigned int u0 = *(const unsigned int*)&Hb[(size_t)d0 * 128 + lane * 2];
        unsigned int u1 = *(const unsigned int*)&Hb[(size_t)d1 * 128 + lane * 2];
        ax += bf2f((unsigned short)(u0 & 0xFFFFu));
        ay += bf2f((unsigned short)(u0 >> 16));
        bx += bf2f((unsigned short)(u1 & 0xFFFFu));
        by += bf2f((unsigned short)(u1 >> 16));
    }
    if (i < e) {
        int d0 = col[i];
        unsigned int u0 = *(const unsigned int*)&Hb[(size_t)d0 * 128 + lane * 2];
        ax += bf2f((unsigned short)(u0 & 0xFFFFu));
        ay += bf2f((unsigned short)(u0 >> 16));
    }
    float den = (e > s) ? (float)(e - s) : 1.0f;
    *(float2*)&out[(size_t)b * 128 + lane * 2] =
        make_float2((ax + bx) / den, (ay + by) / den);
}

extern "C" void kernel_launch(void* const* d_in, const int* in_sizes, int n_in,
                              void* d_out, int out_size, void* d_ws, size_t ws_size,
                              hipStream_t stream)
{
    const int*   edges    = (const int*)d_in[0];
    const int*   node_idx = (const int*)d_in[1];
    const float* X        = (const float*)d_in[2];
    const float* W1       = (const float*)d_in[3];
    const float* b1       = (const float*)d_in[4];
    const float* W2       = (const float*)d_in[5];
    const float* b2       = (const float*)d_in[6];
    const int*   indp     = (const int*)d_in[7];

    const int E = in_sizes[0] / 2;
    const int B = in_sizes[1];
    const int N = in_sizes[2] / IN_DIM;
    const int nb = (N + SCAN_CHUNK - 1) / SCAN_CHUNK;   // 49

    // workspace layout:
    // [deg N][cursor N][16B] | [bsum nb][bbase nb] [rowstart N+1]
    // [Hb N*128 bf16][col E u16] [Wt1][Wt2] (each 16384 bf16)
    char* ws = (char*)d_ws;
    size_t off = 0;
    int* deg    = (int*)(ws + off); off += (size_t)N * 4;
    int* cursor = (int*)(ws + off); off += (size_t)N * 4;
    off += 16;
    const size_t zbytes = off;
    int* bsum  = (int*)(ws + off); off += (size_t)nb * 4;
    int* bbase = (int*)(ws + off); off += (size_t)nb * 4;
    off = (off + 15) & ~(size_t)15;
    int* rowstart = (int*)(ws + off); off += (size_t)(N + 1) * 4;
    off = (off + 15) & ~(size_t)15;
    unsigned short* Hb = (unsigned short*)(ws + off); off += (size_t)N * IN_DIM * 2;
    unsigned short* col = (unsigned short*)(ws + off); off += (size_t)E * 2;
    off = (off + 15) & ~(size_t)15;
    unsigned short* Wt1 = (unsigned short*)(ws + off); off += 16384 * 2;
    unsigned short* Wt2 = (unsigned short*)(ws + off); off += 16384 * 2;

    hipMemsetAsync(d_ws, 0, zbytes, stream);

    hipLaunchKernelGGL(setup, dim3(128), dim3(256), 0, stream,
                       W1, W2, Wt1, Wt2);
    hipLaunchKernelGGL(mlp_mfma, dim3((N + 127) / 128), dim3(256), 0, stream,
                       X, Wt1, Wt2, b1, b2, Hb, N);
    hipLaunchKernelGGL(edge_count, dim3((E + 255) / 256), dim3(256), 0, stream,
                       edges, indp, deg, E);
    hipLaunchKernelGGL(scan1, dim3(nb), dim3(256), 0, stream,
                       deg, rowstart, bsum, N);
    hipLaunchKernelGGL(scan2, dim3(1), dim3(64), 0, stream,
                       bsum, bbase, rowstart, nb, N);
    hipLaunchKernelGGL(scan3, dim3((N + 255) / 256), dim3(256), 0, stream,
                       rowstart, bbase, N);
    hipLaunchKernelGGL(edge_fill_csr, dim3((E + 255) / 256), dim3(256), 0,
                       stream, edges, indp, rowstart, cursor, col, E);
    hipLaunchKernelGGL(aggregate_out, dim3((B * 64 + 255) / 256), dim3(256), 0,
                       stream, node_idx, rowstart, col, Hb, (float*)d_out, B);
}

// Round 8
// 176.761 us; speedup vs baseline: 1.5845x; 1.2124x over previous
//
#include <hip/hip_runtime.h>

#define IN_DIM 128
#define CAP 128           // adjacency bucket capacity (deg~Poisson(16); P(>=128)~1e-120)
#define LDT 136           // padded per-wave scratch row stride (ushorts)

typedef short v8s __attribute__((ext_vector_type(8)));   // 8 bf16 (4 VGPRs)
typedef float v4f __attribute__((ext_vector_type(4)));   // MFMA acc

__device__ inline unsigned short f2bf(float f) {
    unsigned int u = __float_as_uint(f);
    u += 0x7FFFu + ((u >> 16) & 1u);          // round-to-nearest-even
    return (unsigned short)(u >> 16);
}
__device__ inline float bf2f(unsigned short h) {
    return __uint_as_float((unsigned int)h << 16);
}

// ---------------------------------------------------------------------------
// Fused setup + edge fill (replaces edge_count/scan1/scan2/scan3/edge_fill_csr
// — R7 showed the 9-dispatch chain itself was the bottleneck, ~130us of
// serialization for ~80us of kernel work).
// Blocks [0,128): W1/W2 fp32 (k-major) -> transposed bf16 Wt[n][k].
// Blocks [128,..): bucket-scatter kept edges: col[src*CAP + cursor[src]++]=dst.
// Kept edge: src!=dst or mask[ind]!=0 (mask={1,1,0,0}). deg==row_sum exactly
// (kept weights all 1.0; zero-weight self edges dropped from num AND denom).
// ---------------------------------------------------------------------------
__global__ __launch_bounds__(256) void setup_fill(
    const float* __restrict__ W1, const float* __restrict__ W2,
    unsigned short* __restrict__ Wt1, unsigned short* __restrict__ Wt2,
    const int* __restrict__ edges, const int* __restrict__ indp,
    int* __restrict__ cursor, unsigned short* __restrict__ col, int E)
{
    int bid = blockIdx.x;
    if (bid < 128) {
        int i = bid * 256 + threadIdx.x;   // 0..32767
        int m = i >> 14, rem = i & 16383;
        int n = rem >> 7, k = rem & 127;
        float wv = (m ? W2 : W1)[k * 128 + n];
        (m ? Wt2 : Wt1)[n * 128 + k] = f2bf(wv);
    } else {
        int e = (bid - 128) * 256 + threadIdx.x;
        if (e < E) {
            int2 ed = ((const int2*)edges)[e];
            if (ed.x != ed.y || *indp < 2) {
                int p = atomicAdd(&cursor[ed.x], 1);   // ~16-way/node, cheap
                if (p < CAP)
                    col[(size_t)ed.x * CAP + p] = (unsigned short)ed.y;
            }
        }
    }
}

// ---------------------------------------------------------------------------
// Barrier-free MFMA MLP: Hb = bf16(tanh(X@W1+b1)@W2+b2).
// R5/R7-proven shape: block = 128 rows x 128 cols, 4 waves, wave w owns rows
// [w*32, w*32+32) as 2 row-tiles of 16. Phase-2 A-rows == the wave's own
// phase-1 C-rows -> tanh intermediate is wave-private LDS; NO __syncthreads.
// Single-bf16 W B-frags straight from global (16 KB/chunk L1-resident).
// launch_bounds (256,1): occupancy is grid-limited (1563 waves total =
// 1.5/SIMD) so the VGPR cap buys nothing — give compiler registers to keep
// loads in flight. Frag maps (m89/m91/m120-verified): A[m=lane&15][k=quad*8+j];
// B[n=lane&15][k=quad*8+j]; C/D col=lane&15, row=quad*4+reg.
// ---------------------------------------------------------------------------
__global__ __launch_bounds__(256, 1) void mlp_mfma(
    const float* __restrict__ X,
    const unsigned short* __restrict__ Wt1, const unsigned short* __restrict__ Wt2,
    const float* __restrict__ b1, const float* __restrict__ b2,
    unsigned short* __restrict__ Hb, int nrows)
{
    __shared__ unsigned short Ts[4 * 32 * LDT];   // 34816 B, per-wave slices
    const int t    = threadIdx.x;
    const int w    = t >> 6;
    const int lane = t & 63;
    const int l15  = lane & 15;
    const int quad = lane >> 4;
    const int R0   = blockIdx.x * 128;
    const int wrow = w * 32;
    unsigned short* Tw = &Ts[w * 32 * LDT];

    v4f acc[2][8];
#pragma unroll
    for (int rt = 0; rt < 2; ++rt)
#pragma unroll
        for (int ct = 0; ct < 8; ++ct)
            acc[rt][ct] = (v4f){0.f, 0.f, 0.f, 0.f};

    // ---- phase 1: T = tanh(X @ W1 + b1) ----
#pragma unroll
    for (int kk = 0; kk < 4; ++kk) {
        v8s a[2];
#pragma unroll
        for (int rt = 0; rt < 2; ++rt) {
            int grow = R0 + wrow + rt * 16 + l15;
            grow = grow < nrows ? grow : nrows - 1;
            const float* xp = &X[(size_t)grow * 128 + kk * 32 + quad * 8];
            float4 x0 = *(const float4*)xp;
            float4 x1 = *(const float4*)(xp + 4);
            v8s av;
            av[0] = (short)f2bf(x0.x); av[1] = (short)f2bf(x0.y);
            av[2] = (short)f2bf(x0.z); av[3] = (short)f2bf(x0.w);
            av[4] = (short)f2bf(x1.x); av[5] = (short)f2bf(x1.y);
            av[6] = (short)f2bf(x1.z); av[7] = (short)f2bf(x1.w);
            a[rt] = av;
        }
#pragma unroll
        for (int ct = 0; ct < 8; ++ct) {
            v8s b = *(const v8s*)&Wt1[(size_t)(ct * 16 + l15) * 128 + kk * 32 + quad * 8];
#pragma unroll
            for (int rt = 0; rt < 2; ++rt)
                acc[rt][ct] = __builtin_amdgcn_mfma_f32_16x16x32_bf16(
                    a[rt], b, acc[rt][ct], 0, 0, 0);
        }
    }
    // epilogue 1: tanh -> per-wave LDS (bf16, C-layout scatter)
#pragma unroll
    for (int ct = 0; ct < 8; ++ct) {
        float bias = b1[ct * 16 + l15];
#pragma unroll
        for (int rt = 0; rt < 2; ++rt) {
#pragma unroll
            for (int r = 0; r < 4; ++r)
                Tw[(rt * 16 + quad * 4 + r) * LDT + ct * 16 + l15] =
                    f2bf(tanhf(acc[rt][ct][r] + bias));
            acc[rt][ct] = (v4f){0.f, 0.f, 0.f, 0.f};
        }
    }
    asm volatile("s_waitcnt lgkmcnt(0)" ::: "memory");  // wave-local W->R order

    // ---- phase 2: H = T @ W2 + b2 ----
#pragma unroll
    for (int kk = 0; kk < 4; ++kk) {
        v8s a[2];
#pragma unroll
        for (int rt = 0; rt < 2; ++rt)
            a[rt] = *(const v8s*)&Tw[(rt * 16 + l15) * LDT + kk * 32 + quad * 8];
#pragma unroll
        for (int ct = 0; ct < 8; ++ct) {
            v8s b = *(const v8s*)&Wt2[(size_t)(ct * 16 + l15) * 128 + kk * 32 + quad * 8];
#pragma unroll
            for (int rt = 0; rt < 2; ++rt)
                acc[rt][ct] = __builtin_amdgcn_mfma_f32_16x16x32_bf16(
                    a[rt], b, acc[rt][ct], 0, 0, 0);
        }
    }
    asm volatile("s_waitcnt lgkmcnt(0)" ::: "memory");  // phase-2 reads done
    // epilogue 2: acc -> per-wave LDS (bf16) -> coalesced dwordx4 H stores
#pragma unroll
    for (int ct = 0; ct < 8; ++ct) {
        float bias = b2[ct * 16 + l15];
#pragma unroll
        for (int rt = 0; rt < 2; ++rt)
#pragma unroll
            for (int r = 0; r < 4; ++r)
                Tw[(rt * 16 + quad * 4 + r) * LDT + ct * 16 + l15] =
                    f2bf(acc[rt][ct][r] + bias);
    }
    asm volatile("s_waitcnt lgkmcnt(0)" ::: "memory");
#pragma unroll
    for (int i = 0; i < 8; ++i) {
        int lr = i * 4 + quad;             // 0..31
        int c  = l15;                      // 16 chunks x 8 ushorts = 128
        uint4 v = *(const uint4*)&Tw[lr * LDT + c * 8];
        int grow = R0 + wrow + lr;
        if (grow < nrows)
            *(uint4*)&Hb[(size_t)grow * 128 + c * 8] = v;
    }
}

// ---------------------------------------------------------------------------
// Fused aggregate+gather: one wave per OUTPUT row b. v=node_idx[b];
// out[b] = (sum_i Hb[col[v*CAP+i]]) / max(deg,1), deg = cursor[v].
// Hb bf16: 4B/lane -> 256B coalesced row gather, no atomics. 10000 waves ->
// full occupancy, latency hides.
// ---------------------------------------------------------------------------
__global__ __launch_bounds__(256) void aggregate_out(
    const int* __restrict__ node_idx, const int* __restrict__ cursor,
    const unsigned short* __restrict__ col, const unsigned short* __restrict__ Hb,
    float* __restrict__ out, int B)
{
    int b = (int)((blockIdx.x * blockDim.x + threadIdx.x) >> 6);
    if (b >= B) return;
    int lane = threadIdx.x & 63;
    int v = node_idx[b];
    int deg = cursor[v];
    deg = deg < CAP ? deg : CAP;
    const unsigned short* cp = &col[(size_t)v * CAP];
    float ax = 0.f, ay = 0.f, bx = 0.f, by = 0.f;
    int i = 0;
    for (; i + 1 < deg; i += 2) {
        int d0 = cp[i], d1 = cp[i + 1];
        unsigned int u0 = *(const unsigned int*)&Hb[(size_t)d0 * 128 + lane * 2];
        unsigned int u1 = *(const unsigned int*)&Hb[(size_t)d1 * 128 + lane * 2];
        ax += bf2f((unsigned short)(u0 & 0xFFFFu));
        ay += bf2f((unsigned short)(u0 >> 16));
        bx += bf2f((unsigned short)(u1 & 0xFFFFu));
        by += bf2f((unsigned short)(u1 >> 16));
    }
    if (i < deg) {
        int d0 = cp[i];
        unsigned int u0 = *(const unsigned int*)&Hb[(size_t)d0 * 128 + lane * 2];
        ax += bf2f((unsigned short)(u0 & 0xFFFFu));
        ay += bf2f((unsigned short)(u0 >> 16));
    }
    float den = (deg > 0) ? (float)deg : 1.0f;
    *(float2*)&out[(size_t)b * 128 + lane * 2] =
        make_float2((ax + bx) / den, (ay + by) / den);
}

extern "C" void kernel_launch(void* const* d_in, const int* in_sizes, int n_in,
                              void* d_out, int out_size, void* d_ws, size_t ws_size,
                              hipStream_t stream)
{
    const int*   edges    = (const int*)d_in[0];
    const int*   node_idx = (const int*)d_in[1];
    const float* X        = (const float*)d_in[2];
    const float* W1       = (const float*)d_in[3];
    const float* b1       = (const float*)d_in[4];
    const float* W2       = (const float*)d_in[5];
    const float* b2       = (const float*)d_in[6];
    const int*   indp     = (const int*)d_in[7];

    const int E = in_sizes[0] / 2;
    const int B = in_sizes[1];
    const int N = in_sizes[2] / IN_DIM;

    // workspace layout:
    // [cursor N i32 (memset 0)] | [Hb N*128 bf16][col N*CAP u16][Wt1][Wt2]
    char* ws = (char*)d_ws;
    size_t off = 0;
    int* cursor = (int*)(ws + off); off += (size_t)N * 4;
    const size_t zbytes = off;
    off = (off + 15) & ~(size_t)15;
    unsigned short* Hb  = (unsigned short*)(ws + off); off += (size_t)N * IN_DIM * 2;
    unsigned short* col = (unsigned short*)(ws + off); off += (size_t)N * CAP * 2;
    unsigned short* Wt1 = (unsigned short*)(ws + off); off += 16384 * 2;
    unsigned short* Wt2 = (unsigned short*)(ws + off); off += 16384 * 2;

    hipMemsetAsync(d_ws, 0, zbytes, stream);

    hipLaunchKernelGGL(setup_fill, dim3(128 + (E + 255) / 256), dim3(256), 0,
                       stream, W1, W2, Wt1, Wt2, edges, indp, cursor, col, E);
    hipLaunchKernelGGL(mlp_mfma, dim3((N + 127) / 128), dim3(256), 0, stream,
                       X, Wt1, Wt2, b1, b2, Hb, N);
    hipLaunchKernelGGL(aggregate_out, dim3((B * 64 + 255) / 256), dim3(256), 0,
                       stream, node_idx, cursor, col, Hb, (float*)d_out, B);
}

// Round 9
// 132.077 us; speedup vs baseline: 2.1205x; 1.3383x over previous
//
#include <hip/hip_runtime.h>

#define IN_DIM 128
#define CAP 128           // adjacency bucket capacity (deg~Poisson(16); P(>=128)~1e-120)
#define LDT 136           // padded per-wave scratch row stride (ushorts)

typedef short v8s __attribute__((ext_vector_type(8)));   // 8 bf16 (4 VGPRs)
typedef float v4f __attribute__((ext_vector_type(4)));   // MFMA acc

__device__ inline unsigned short f2bf(float f) {
    unsigned int u = __float_as_uint(f);
    u += 0x7FFFu + ((u >> 16) & 1u);          // round-to-nearest-even
    return (unsigned short)(u >> 16);
}
__device__ inline float bf2f(unsigned short h) {
    return __uint_as_float((unsigned int)h << 16);
}

// ---------------------------------------------------------------------------
// prep: blocks [0,128): W1/W2 fp32 (k-major) -> transposed bf16 Wt[n][k].
// blocks [128,..): flag[node_idx[i]] = 1 (only ~9.2k of 50k nodes are ever
// read by the output gather -> scatter workload shrinks 5.4x downstream).
// Independent sub-grids, no race (flag writes only here, after memset).
// ---------------------------------------------------------------------------
__global__ __launch_bounds__(256) void prep(
    const float* __restrict__ W1, const float* __restrict__ W2,
    unsigned short* __restrict__ Wt1, unsigned short* __restrict__ Wt2,
    const int* __restrict__ node_idx, int* __restrict__ flag, int B)
{
    int bid = blockIdx.x;
    if (bid < 128) {
        int i = bid * 256 + threadIdx.x;   // 0..32767
        int m = i >> 14, rem = i & 16383;
        int n = rem >> 7, k = rem & 127;
        float wv = (m ? W2 : W1)[k * 128 + n];
        (m ? Wt2 : Wt1)[n * 128 + k] = f2bf(wv);
    } else {
        int i = (bid - 128) * 256 + threadIdx.x;
        if (i < B) flag[node_idx[i]] = 1;
    }
}

// ---------------------------------------------------------------------------
// Fused MLP + edge scatter (one dispatch, two independent sub-grids that
// only depend on prep). mlp blocks FIRST (the long pole, MFMA/VMEM-bound);
// scatter blocks after (latency-bound, ~0.5% VALU) — different pipes, so
// the scatter hides in the MLP's shadow (m114 co-scheduling).
//
// MLP sub-grid (R5/R7-proven shape): Hb = bf16(tanh(X@W1+b1)@W2+b2).
// Block = 128 rows x 128 cols, 4 waves, wave w owns rows [w*32,w*32+32) as
// 2 row-tiles of 16. Phase-2 A-rows == the wave's own phase-1 C-rows ->
// tanh intermediate is wave-private LDS; NO __syncthreads. Single-bf16 W
// B-frags straight from global (16 KB/chunk L1-resident).
// Frag maps (m89/m91/m120-verified): A[m=lane&15][k=quad*8+j];
// B[n=lane&15][k=quad*8+j]; C/D col=lane&15, row=quad*4+reg.
//
// Scatter sub-grid: kept edge (src!=dst or mask[ind]!=0) with flagged src:
// col[src*CAP + cursor[src]++] = dst. deg==row_sum exactly (kept weights
// all 1.0; zero-weight self edges dropped from num AND denom).
// ---------------------------------------------------------------------------
__global__ __launch_bounds__(256, 1) void mlp_fill(
    const float* __restrict__ X,
    const unsigned short* __restrict__ Wt1, const unsigned short* __restrict__ Wt2,
    const float* __restrict__ b1, const float* __restrict__ b2,
    unsigned short* __restrict__ Hb, int nrows,
    const int* __restrict__ edges, const int* __restrict__ flag,
    const int* __restrict__ indp, int* __restrict__ cursor,
    unsigned short* __restrict__ col, int E, int mlpBlocks)
{
    __shared__ unsigned short Ts[4 * 32 * LDT];   // 34816 B, per-wave slices
    const int bid = blockIdx.x;

    if (bid >= mlpBlocks) {
        // ---- edge scatter ----
        int e = (bid - mlpBlocks) * 256 + threadIdx.x;
        if (e < E) {
            int2 ed = ((const int2*)edges)[e];
            if ((ed.x != ed.y || *indp < 2) && flag[ed.x] != 0) {
                int p = atomicAdd(&cursor[ed.x], 1);   // ~16-way/node, cheap
                if (p < CAP)
                    col[(size_t)ed.x * CAP + p] = (unsigned short)ed.y;
            }
        }
        return;
    }

    // ---- MLP ----
    const int t    = threadIdx.x;
    const int w    = t >> 6;
    const int lane = t & 63;
    const int l15  = lane & 15;
    const int quad = lane >> 4;
    const int R0   = bid * 128;
    const int wrow = w * 32;
    unsigned short* Tw = &Ts[w * 32 * LDT];

    v4f acc[2][8];
#pragma unroll
    for (int rt = 0; rt < 2; ++rt)
#pragma unroll
        for (int ct = 0; ct < 8; ++ct)
            acc[rt][ct] = (v4f){0.f, 0.f, 0.f, 0.f};

    // phase 1: T = tanh(X @ W1 + b1)
#pragma unroll
    for (int kk = 0; kk < 4; ++kk) {
        v8s a[2];
#pragma unroll
        for (int rt = 0; rt < 2; ++rt) {
            int grow = R0 + wrow + rt * 16 + l15;
            grow = grow < nrows ? grow : nrows - 1;
            const float* xp = &X[(size_t)grow * 128 + kk * 32 + quad * 8];
            float4 x0 = *(const float4*)xp;
            float4 x1 = *(const float4*)(xp + 4);
            v8s av;
            av[0] = (short)f2bf(x0.x); av[1] = (short)f2bf(x0.y);
            av[2] = (short)f2bf(x0.z); av[3] = (short)f2bf(x0.w);
            av[4] = (short)f2bf(x1.x); av[5] = (short)f2bf(x1.y);
            av[6] = (short)f2bf(x1.z); av[7] = (short)f2bf(x1.w);
            a[rt] = av;
        }
#pragma unroll
        for (int ct = 0; ct < 8; ++ct) {
            v8s b = *(const v8s*)&Wt1[(size_t)(ct * 16 + l15) * 128 + kk * 32 + quad * 8];
#pragma unroll
            for (int rt = 0; rt < 2; ++rt)
                acc[rt][ct] = __builtin_amdgcn_mfma_f32_16x16x32_bf16(
                    a[rt], b, acc[rt][ct], 0, 0, 0);
        }
    }
    // epilogue 1: tanh -> per-wave LDS (bf16, C-layout scatter)
#pragma unroll
    for (int ct = 0; ct < 8; ++ct) {
        float bias = b1[ct * 16 + l15];
#pragma unroll
        for (int rt = 0; rt < 2; ++rt) {
#pragma unroll
            for (int r = 0; r < 4; ++r)
                Tw[(rt * 16 + quad * 4 + r) * LDT + ct * 16 + l15] =
                    f2bf(tanhf(acc[rt][ct][r] + bias));
            acc[rt][ct] = (v4f){0.f, 0.f, 0.f, 0.f};
        }
    }
    asm volatile("s_waitcnt lgkmcnt(0)" ::: "memory");  // wave-local W->R order

    // phase 2: H = T @ W2 + b2
#pragma unroll
    for (int kk = 0; kk < 4; ++kk) {
        v8s a[2];
#pragma unroll
        for (int rt = 0; rt < 2; ++rt)
            a[rt] = *(const v8s*)&Tw[(rt * 16 + l15) * LDT + kk * 32 + quad * 8];
#pragma unroll
        for (int ct = 0; ct < 8; ++ct) {
            v8s b = *(const v8s*)&Wt2[(size_t)(ct * 16 + l15) * 128 + kk * 32 + quad * 8];
#pragma unroll
            for (int rt = 0; rt < 2; ++rt)
                acc[rt][ct] = __builtin_amdgcn_mfma_f32_16x16x32_bf16(
                    a[rt], b, acc[rt][ct], 0, 0, 0);
        }
    }
    asm volatile("s_waitcnt lgkmcnt(0)" ::: "memory");  // phase-2 reads done
    // epilogue 2: acc -> per-wave LDS (bf16) -> coalesced dwordx4 H stores
#pragma unroll
    for (int ct = 0; ct < 8; ++ct) {
        float bias = b2[ct * 16 + l15];
#pragma unroll
        for (int rt = 0; rt < 2; ++rt)
#pragma unroll
            for (int r = 0; r < 4; ++r)
                Tw[(rt * 16 + quad * 4 + r) * LDT + ct * 16 + l15] =
                    f2bf(acc[rt][ct][r] + bias);
    }
    asm volatile("s_waitcnt lgkmcnt(0)" ::: "memory");
#pragma unroll
    for (int i = 0; i < 8; ++i) {
        int lr = i * 4 + quad;             // 0..31
        int c  = l15;                      // 16 chunks x 8 ushorts = 128
        uint4 v = *(const uint4*)&Tw[lr * LDT + c * 8];
        int grow = R0 + wrow + lr;
        if (grow < nrows)
            *(uint4*)&Hb[(size_t)grow * 128 + c * 8] = v;
    }
}

// ---------------------------------------------------------------------------
// Fused aggregate+gather: one wave per OUTPUT row b. v=node_idx[b];
// out[b] = (sum_i Hb[col[v*CAP+i]]) / max(deg,1), deg = cursor[v].
// Hb bf16: 4B/lane -> 256B coalesced row gather, no atomics. 10000 waves.
// ---------------------------------------------------------------------------
__global__ __launch_bounds__(256) void aggregate_out(
    const int* __restrict__ node_idx, const int* __restrict__ cursor,
    const unsigned short* __restrict__ col, const unsigned short* __restrict__ Hb,
    float* __restrict__ out, int B)
{
    int b = (int)((blockIdx.x * blockDim.x + threadIdx.x) >> 6);
    if (b >= B) return;
    int lane = threadIdx.x & 63;
    int v = node_idx[b];
    int deg = cursor[v];
    deg = deg < CAP ? deg : CAP;
    const unsigned short* cp = &col[(size_t)v * CAP];
    float ax = 0.f, ay = 0.f, bx = 0.f, by = 0.f;
    int i = 0;
    for (; i + 1 < deg; i += 2) {
        int d0 = cp[i], d1 = cp[i + 1];
        unsigned int u0 = *(const unsigned int*)&Hb[(size_t)d0 * 128 + lane * 2];
        unsigned int u1 = *(const unsigned int*)&Hb[(size_t)d1 * 128 + lane * 2];
        ax += bf2f((unsigned short)(u0 & 0xFFFFu));
        ay += bf2f((unsigned short)(u0 >> 16));
        bx += bf2f((unsigned short)(u1 & 0xFFFFu));
        by += bf2f((unsigned short)(u1 >> 16));
    }
    if (i < deg) {
        int d0 = cp[i];
        unsigned int u0 = *(const unsigned int*)&Hb[(size_t)d0 * 128 + lane * 2];
        ax += bf2f((unsigned short)(u0 & 0xFFFFu));
        ay += bf2f((unsigned short)(u0 >> 16));
    }
    float den = (deg > 0) ? (float)deg : 1.0f;
    *(float2*)&out[(size_t)b * 128 + lane * 2] =
        make_float2((ax + bx) / den, (ay + by) / den);
}

extern "C" void kernel_launch(void* const* d_in, const int* in_sizes, int n_in,
                              void* d_out, int out_size, void* d_ws, size_t ws_size,
                              hipStream_t stream)
{
    const int*   edges    = (const int*)d_in[0];
    const int*   node_idx = (const int*)d_in[1];
    const float* X        = (const float*)d_in[2];
    const float* W1       = (const float*)d_in[3];
    const float* b1       = (const float*)d_in[4];
    const float* W2       = (const float*)d_in[5];
    const float* b2       = (const float*)d_in[6];
    const int*   indp     = (const int*)d_in[7];

    const int E = in_sizes[0] / 2;
    const int B = in_sizes[1];
    const int N = in_sizes[2] / IN_DIM;
    const int mlpBlocks = (N + 127) / 128;   // 391

    // workspace layout:
    // [cursor N i32][flag N i32] (memset 0) | [Hb N*128 bf16][col N*CAP u16]
    // [Wt1][Wt2] (each 16384 bf16)
    char* ws = (char*)d_ws;
    size_t off = 0;
    int* cursor = (int*)(ws + off); off += (size_t)N * 4;
    int* flag   = (int*)(ws + off); off += (size_t)N * 4;
    const size_t zbytes = off;
    off = (off + 15) & ~(size_t)15;
    unsigned short* Hb  = (unsigned short*)(ws + off); off += (size_t)N * IN_DIM * 2;
    unsigned short* col = (unsigned short*)(ws + off); off += (size_t)N * CAP * 2;
    unsigned short* Wt1 = (unsigned short*)(ws + off); off += 16384 * 2;
    unsigned short* Wt2 = (unsigned short*)(ws + off); off += 16384 * 2;

    hipMemsetAsync(d_ws, 0, zbytes, stream);

    hipLaunchKernelGGL(prep, dim3(128 + (B + 255) / 256), dim3(256), 0, stream,
                       W1, W2, Wt1, Wt2, node_idx, flag, B);
    hipLaunchKernelGGL(mlp_fill, dim3(mlpBlocks + (E + 255) / 256), dim3(256),
                       0, stream, X, Wt1, Wt2, b1, b2, Hb, N,
                       edges, flag, indp, cursor, col, E, mlpBlocks);
    hipLaunchKernelGGL(aggregate_out, dim3((B * 64 + 255) / 256), dim3(256), 0,
                       stream, node_idx, cursor, col, Hb, (float*)d_out, B);
}